// Round 7
// baseline (83.962 us; speedup 1.0000x reference)
//
#include <hip/hip_runtime.h>

#define EPSF 1e-8f

constexpr int B_  = 16;
constexpr int C_  = 32;
constexpr int O_  = 32;
constexpr int HW  = 196;    // 14*14
constexpr int T9  = 9;
constexpr int CH  = 64;     // hw rows per chunk: 64,64,64,4
constexpr int ROWF = 12;    // padded floats per (hw,t) row
constexpr int LDSF = CH * T9 * ROWF;      // 6912 floats = 27648 B
constexpr int KSPL = 2;                   // chunk-chain split across blocks
constexpr int PW  = C_ * KSPL;            // 64 partials per (b,o,t)
constexpr int P1_N = B_ * O_ * T9 * PW;   // 294912
constexpr int P2_N = B_ * O_ * PW;        // 32768
constexpr int XT_N = C_ * B_ * 9 * HW;    // 903168
constexpr int PT_N = C_ * B_ * HW;        // 100352

// ---------------------------------------------------------------------------
// Kernel P: x -> xT[c][b][s][hw] (x0.1 folded), p -> pT[c][b][hw].
// Makes every kernel-A global read lane-contiguous.
// ---------------------------------------------------------------------------
__global__ __launch_bounds__(256) void caps_pre(
    const float* __restrict__ x, const float* __restrict__ p,
    float* __restrict__ xT, float* __restrict__ pT)
{
    const int idx = blockIdx.x * 256 + threadIdx.x;
    const int stride = gridDim.x * 256;
    for (int m = idx; m < XT_N; m += stride) {
        const int hw = m % HW;
        const int r  = m / HW;       // (c*16+b)*9+s
        const int s  = r % 9;
        const int r2 = r / 9;        // c*16+b
        const int b  = r2 % B_;
        const int c  = r2 / B_;
        xT[m] = 0.1f * x[((size_t)(b * C_ + c) * HW + hw) * 9 + s];
    }
    for (int m = idx; m < PT_N; m += stride) {
        const int hw = m % HW;
        const int r2 = m / HW;
        const int b  = r2 % B_;
        const int c  = r2 / B_;
        pT[m] = p[(size_t)(b * C_ + c) * HW + hw];
    }
}

// ---------------------------------------------------------------------------
// Kernel A: block = (o, c, z). z=0 -> chunks {0,1}, z=1 -> chunks {2,3}.
// 256 threads = 4 waves; wave bg owns b = bg*4..bg*4+3 (J=4 register block);
// lane = hw row within chunk. Each LDS T-row read feeds 4 b's -> LDS-pipe
// instr count / 4 vs J=1. Second moment folded over t in-loop (only the
// t-sum is needed downstream) -> 40-value cross-lane reduce, low VGPR.
// ---------------------------------------------------------------------------
__global__ __launch_bounds__(256) void caps_main(
    const float* __restrict__ T,
    const float* __restrict__ xT, const float* __restrict__ pT,
    float* __restrict__ part1,    // [b][o][t][c*2+z]
    float* __restrict__ part2s)   // [b][o][c*2+z]  (t-summed 2nd moment)
{
    const int o    = blockIdx.x;
    const int c    = blockIdx.y;
    const int z    = blockIdx.z;
    const int tid  = threadIdx.x;
    const int bg   = tid >> 6;    // wave id 0..3
    const int lane = tid & 63;    // hw row within chunk

    __shared__ float tsh[LDSF];

    const float* Tb = T + (size_t)(c * O_ + o) * (HW * 81);

    float acc1[4][9];
    float a2s[4];
#pragma unroll
    for (int j = 0; j < 4; ++j) {
        a2s[j] = 0.f;
#pragma unroll
        for (int t = 0; t < 9; ++t) acc1[j][t] = 0.f;
    }

    const int k0 = z * 2;
    for (int k = k0; k < k0 + 2; ++k) {
        const int hw0 = k * CH;
        const int R   = (HW - hw0 < CH) ? (HW - hw0) : CH;   // 64 or 4
        if (k != k0) __syncthreads();

        // stage chunk k: coalesced float4 global read, padded scatter to LDS
        const int nf4 = (R * 81) >> 2;   // 1296 or 81 (both exact)
        const float4* g4 = (const float4*)(Tb + (size_t)hw0 * 81);
        for (int i = tid; i < nf4; i += 256) {
            const float4 v = g4[i];
            const int e = i * 4;
#pragma unroll
            for (int k2 = 0; k2 < 4; ++k2) {
                const int e2 = e + k2;
                tsh[e2 + 3 * (e2 / 9)] = ((const float*)&v)[k2];
            }
        }
        __syncthreads();

        if (lane < R) {
            const int hw = hw0 + lane;
            float xr[4][9], pw[4];
#pragma unroll
            for (int j = 0; j < 4; ++j) {
                const int b = bg * 4 + j;
                const float* xg = xT + (size_t)(c * B_ + b) * 9 * HW + hw;
#pragma unroll
                for (int s = 0; s < 9; ++s) xr[j][s] = xg[(size_t)s * HW];
                pw[j] = pT[(size_t)(c * B_ + b) * HW + hw];
            }
            const float* rowb = tsh + lane * (T9 * ROWF);
#pragma unroll
            for (int t = 0; t < 9; ++t) {
                const float4 ta  = *(const float4*)(rowb + t * ROWF);
                const float4 tb4 = *(const float4*)(rowb + t * ROWF + 4);
                const float t8   = rowb[t * ROWF + 8];
#pragma unroll
                for (int j = 0; j < 4; ++j) {
                    float pr = ta.x * xr[j][0];
                    pr = fmaf(ta.y,  xr[j][1], pr);
                    pr = fmaf(ta.z,  xr[j][2], pr);
                    pr = fmaf(ta.w,  xr[j][3], pr);
                    pr = fmaf(tb4.x, xr[j][4], pr);
                    pr = fmaf(tb4.y, xr[j][5], pr);
                    pr = fmaf(tb4.z, xr[j][6], pr);
                    pr = fmaf(tb4.w, xr[j][7], pr);
                    pr = fmaf(t8,    xr[j][8], pr);
                    const float q1 = pw[j] * pr;
                    acc1[j][t] += q1;
                    a2s[j] = fmaf(q1, pr, a2s[j]);   // t-folded 2nd moment
                }
            }
        }
    }

    // 64-lane butterfly reduce: 4 b x (9 acc1 + 1 a2s) = 40 values
#pragma unroll
    for (int j = 0; j < 4; ++j) {
        const int b = bg * 4 + j;
#pragma unroll
        for (int t = 0; t < 9; ++t) {
            float v = acc1[j][t];
#pragma unroll
            for (int m = 1; m < 64; m <<= 1) v += __shfl_xor(v, m, 64);
            if (lane == 0)
                part1[((size_t)(b * O_ + o) * 9 + t) * PW + c * KSPL + z] = v;
        }
        float v2 = a2s[j];
#pragma unroll
        for (int m = 1; m < 64; m <<= 1) v2 += __shfl_xor(v2, m, 64);
        if (lane == 0)
            part2s[(size_t)(b * O_ + o) * PW + c * KSPL + z] = v2;
    }
}

// ---------------------------------------------------------------------------
// Kernel B: per-b finalize. psum; s1 per (o,t) from part1; caps out;
// vs = (sum_t s2 - 2*sum_t caps*s1 + psum*sum_t caps^2)/denom; p_updated.
// ---------------------------------------------------------------------------
__global__ __launch_bounds__(256) void caps_final(
    const float* __restrict__ p,
    const float* __restrict__ part1, const float* __restrict__ part2s,
    float* __restrict__ out)          // caps [B][O][9] then p_updated [B][O]
{
    const int b   = blockIdx.x;
    const int tid = threadIdx.x;

    __shared__ float w1[O_ * T9];
    __shared__ float w2[O_ * T9];
    __shared__ float red[4];
    __shared__ float s_psum;

    const float* pb = p + (size_t)b * (C_ * HW);
    float a = 0.f;
    for (int i = tid; i < C_ * HW; i += 256) a += pb[i];
#pragma unroll
    for (int m = 1; m < 64; m <<= 1) a += __shfl_xor(a, m, 64);
    if ((tid & 63) == 0) red[tid >> 6] = a;
    __syncthreads();
    if (tid == 0) s_psum = (red[0] + red[1]) + (red[2] + red[3]);
    __syncthreads();
    const float psum  = s_psum;
    const float denom = psum + EPSF;

    for (int e = tid; e < O_ * T9; e += 256) {
        const float4* q1 = (const float4*)(part1 + (size_t)(b * 288 + e) * PW);
        float s1 = 0.f;
#pragma unroll
        for (int i = 0; i < PW / 4; ++i) {
            const float4 v = q1[i];
            s1 += (v.x + v.y) + (v.z + v.w);
        }
        const float caps = s1 / denom;
        out[(size_t)b * 288 + e] = caps;
        w1[e] = caps * s1;
        w2[e] = caps * caps;
    }
    __syncthreads();

    if (tid < O_) {
        const int o = tid;
        const float4* q2 = (const float4*)(part2s + (size_t)(b * O_ + o) * PW);
        float s2 = 0.f;
#pragma unroll
        for (int i = 0; i < PW / 4; ++i) {
            const float4 v = q2[i];
            s2 += (v.x + v.y) + (v.z + v.w);
        }
        float d2 = 0.f, dc = 0.f;
#pragma unroll
        for (int t = 0; t < 9; ++t) { d2 += w1[o * 9 + t]; dc += w2[o * 9 + t]; }
        float vs = (s2 - 2.f * d2 + psum * dc) / denom;
        float mx = vs;
#pragma unroll
        for (int msk = 1; msk < 32; msk <<= 1) mx = fmaxf(mx, __shfl_xor(mx, msk, 32));
        out[(size_t)B_ * O_ * T9 + b * O_ + o] = 1.f - vs / (mx + EPSF);
    }
}

extern "C" void kernel_launch(void* const* d_in, const int* in_sizes, int n_in,
                              void* d_out, int out_size, void* d_ws, size_t ws_size,
                              hipStream_t stream)
{
    (void)in_sizes; (void)n_in; (void)out_size; (void)ws_size;
    const float* x = (const float*)d_in[0];   // (16,32,14,14,9)
    const float* p = (const float*)d_in[1];   // (16,32,14,14)
    // d_in[2] = epoch (unused)
    const float* T = (const float*)d_in[3];   // (1,32,32,14,14,9,9)
    float* out = (float*)d_out;

    float* part1  = (float*)d_ws;
    float* part2s = part1 + P1_N;
    float* xT     = part2s + P2_N;
    float* pT     = xT + XT_N;

    caps_pre<<<1024, 256, 0, stream>>>(x, p, xT, pT);
    dim3 gridA(O_, C_, KSPL);  // o fast; same-c blocks adjacent -> L2 reuse of xT
    caps_main<<<gridA, 256, 0, stream>>>(T, xT, pT, part1, part2s);
    caps_final<<<B_, 256, 0, stream>>>(p, part1, part2s, out);
}

// Round 8
// 83.262 us; speedup vs baseline: 1.0084x; 1.0084x over previous
//
#include <hip/hip_runtime.h>

#define EPSF 1e-8f

constexpr int B_  = 16;
constexpr int C_  = 32;
constexpr int O_  = 32;
constexpr int HW  = 196;    // 14*14
constexpr int T9  = 9;
constexpr int PW   = C_ * 4;              // partials per (b,o,t): c x wave
constexpr int P1_N = B_ * O_ * T9 * PW;   // 589824
constexpr int P2_N = B_ * O_ * PW;        // 65536
constexpr int XT_N = C_ * B_ * 9 * HW;    // 903168
constexpr int PT_N = C_ * B_ * HW;        // 100352

// ---------------------------------------------------------------------------
// Kernel P: x -> xT[c][b][s][hw] (x0.1 folded), p -> pT[c][b][hw].
// Makes every kernel-A global read lane-contiguous.
// ---------------------------------------------------------------------------
__global__ __launch_bounds__(256) void caps_pre(
    const float* __restrict__ x, const float* __restrict__ p,
    float* __restrict__ xT, float* __restrict__ pT)
{
    const int idx = blockIdx.x * 256 + threadIdx.x;
    const int stride = gridDim.x * 256;
    for (int m = idx; m < XT_N; m += stride) {
        const int hw = m % HW;
        const int r  = m / HW;       // (c*16+b)*9+s
        const int s  = r % 9;
        const int r2 = r / 9;        // c*16+b
        const int b  = r2 % B_;
        const int c  = r2 / B_;
        xT[m] = 0.1f * x[((size_t)(b * C_ + c) * HW + hw) * 9 + s];
    }
    for (int m = idx; m < PT_N; m += stride) {
        const int hw = m % HW;
        const int r2 = m / HW;
        const int b  = r2 % B_;
        const int c  = r2 / B_;
        pT[m] = p[(size_t)(b * C_ + c) * HW + hw];
    }
}

// ---------------------------------------------------------------------------
// Kernel A: block (o,c) = 1024 blocks, all co-resident (4 blocks/CU).
// BARRIER-FREE: each wave owns a private LDS sub-buffer and an hw slice
// (rows 48w..; 48,48,48,52). Per 16-row chunk: write prefetched T regs to
// padded LDS -> issue x loads -> issue NEXT T prefetch (stays in flight,
// in-order vmcnt: x consume waits vmcnt(6) only) -> J=4 FMA block.
// lane: bg=lane>>4 (b-group), r16=lane&15 (row). LDS row reads broadcast
// across bg groups; 16-lane 4-step butterfly epilogue.
// ---------------------------------------------------------------------------
__global__ __launch_bounds__(256) void caps_main(
    const float* __restrict__ T,
    const float* __restrict__ xT, const float* __restrict__ pT,
    float* __restrict__ part1,    // [b][o][t][c*4+w]
    float* __restrict__ part2s)   // [b][o][c*4+w]  (t-summed 2nd moment)
{
    const int o    = blockIdx.x;
    const int c    = blockIdx.y;
    const int tid  = threadIdx.x;
    const int w    = tid >> 6;    // wave id 0..3
    const int lane = tid & 63;
    const int bg   = lane >> 4;   // b-group 0..3
    const int r16  = lane & 15;   // row within chunk

    __shared__ float tsh[4][16 * T9 * 12];   // per-wave 1728 floats (6912 B)
    float* myl = tsh[w];

    const int slice0 = w * 48;               // rows 48,48,48,52
    const int kmax   = (w < 3) ? 3 : 4;      // chunks of 16 (+4 for wave 3)

    const float* Tb = T + (size_t)(c * O_ + o) * (HW * 81) + (size_t)slice0 * 81;

    const float* xb[4];
    const float* pb[4];
#pragma unroll
    for (int j = 0; j < 4; ++j) {
        const int b = bg * 4 + j;
        xb[j] = xT + (size_t)(c * B_ + b) * 9 * HW;
        pb[j] = pT + (size_t)(c * B_ + b) * HW;
    }

    float acc1[4][9], a2s[4];
#pragma unroll
    for (int j = 0; j < 4; ++j) {
        a2s[j] = 0.f;
#pragma unroll
        for (int t = 0; t < 9; ++t) acc1[j][t] = 0.f;
    }

    // prefetch chunk 0 (16 rows = 324 float4; all chunk bases 16B-aligned)
    float4 pf[6];
    {
        const float4* g4 = (const float4*)Tb;
#pragma unroll
        for (int q = 0; q < 6; ++q) {
            const int i = lane + 64 * q;
            if (i < 324) pf[q] = g4[i];
        }
    }

    for (int k = 0;;) {
        const int rows = (k < 3) ? 16 : 4;
        const int nf4  = rows * 81 / 4;      // 324 or 81

        // 1) write pf (chunk k) into padded LDS [row][t][12]
#pragma unroll
        for (int q = 0; q < 6; ++q) {
            const int i = lane + 64 * q;
            if (i < nf4) {
                const int e = 4 * i;
#pragma unroll
                for (int k2 = 0; k2 < 4; ++k2) {
                    const int e2 = e + k2;
                    myl[e2 + 3 * (e2 / 9)] = ((const float*)&pf[q])[k2];
                }
            }
        }

        // 2) x/p loads for this chunk's row (coalesced scalar dwords)
        const int  hw  = slice0 + k * 16 + r16;
        const bool act = (r16 < rows);
        float xr[4][9], pw4[4];
        if (act) {
#pragma unroll
            for (int j = 0; j < 4; ++j) {
#pragma unroll
                for (int s = 0; s < 9; ++s) xr[j][s] = xb[j][(size_t)s * HW + hw];
                pw4[j] = pb[j][hw];
            }
        }

        // 3) prefetch next chunk (issued after x loads: stays in flight)
        const int kn = k + 1;
        if (kn < kmax) {
            const int nfn = ((kn < 3) ? 16 : 4) * 81 / 4;
            const float4* g4 = (const float4*)(Tb + (size_t)kn * 16 * 81);
#pragma unroll
            for (int q = 0; q < 6; ++q) {
                const int i = lane + 64 * q;
                if (i < nfn) pf[q] = g4[i];
            }
        }

        // 4) compute chunk k
        if (act) {
            const float* rowb = myl + r16 * 108;
#pragma unroll
            for (int t = 0; t < 9; ++t) {
                const float4 ta  = *(const float4*)(rowb + t * 12);
                const float4 tb4 = *(const float4*)(rowb + t * 12 + 4);
                const float  t8  = rowb[t * 12 + 8];
#pragma unroll
                for (int j = 0; j < 4; ++j) {
                    float pr = ta.x * xr[j][0];
                    pr = fmaf(ta.y,  xr[j][1], pr);
                    pr = fmaf(ta.z,  xr[j][2], pr);
                    pr = fmaf(ta.w,  xr[j][3], pr);
                    pr = fmaf(tb4.x, xr[j][4], pr);
                    pr = fmaf(tb4.y, xr[j][5], pr);
                    pr = fmaf(tb4.z, xr[j][6], pr);
                    pr = fmaf(tb4.w, xr[j][7], pr);
                    pr = fmaf(t8,    xr[j][8], pr);
                    const float q1 = pw4[j] * pr;
                    acc1[j][t] += q1;
                    a2s[j] = fmaf(q1, pr, a2s[j]);
                }
            }
        }

        if (++k >= kmax) break;
    }

    // epilogue: 4-step butterfly over the 16 row-lanes (lane bits 0..3)
#pragma unroll
    for (int j = 0; j < 4; ++j) {
        const int b = bg * 4 + j;
#pragma unroll
        for (int t = 0; t < 9; ++t) {
            float v = acc1[j][t];
            v += __shfl_xor(v, 1, 64);
            v += __shfl_xor(v, 2, 64);
            v += __shfl_xor(v, 4, 64);
            v += __shfl_xor(v, 8, 64);
            if (r16 == 0)
                part1[((size_t)(b * O_ + o) * 9 + t) * PW + c * 4 + w] = v;
        }
        float v2 = a2s[j];
        v2 += __shfl_xor(v2, 1, 64);
        v2 += __shfl_xor(v2, 2, 64);
        v2 += __shfl_xor(v2, 4, 64);
        v2 += __shfl_xor(v2, 8, 64);
        if (r16 == 0)
            part2s[(size_t)(b * O_ + o) * PW + c * 4 + w] = v2;
    }
}

// ---------------------------------------------------------------------------
// Kernel B: per-b finalize. psum; s1 per (o,t); caps out;
// vs = (sum_t s2 - 2*sum_t caps*s1 + psum*sum_t caps^2)/denom; p_updated.
// ---------------------------------------------------------------------------
__global__ __launch_bounds__(256) void caps_final(
    const float* __restrict__ p,
    const float* __restrict__ part1, const float* __restrict__ part2s,
    float* __restrict__ out)          // caps [B][O][9] then p_updated [B][O]
{
    const int b   = blockIdx.x;
    const int tid = threadIdx.x;

    __shared__ float w1[O_ * T9];
    __shared__ float w2[O_ * T9];
    __shared__ float red[4];
    __shared__ float s_psum;

    const float* pb = p + (size_t)b * (C_ * HW);
    float a = 0.f;
    for (int i = tid; i < C_ * HW; i += 256) a += pb[i];
#pragma unroll
    for (int m = 1; m < 64; m <<= 1) a += __shfl_xor(a, m, 64);
    if ((tid & 63) == 0) red[tid >> 6] = a;
    __syncthreads();
    if (tid == 0) s_psum = (red[0] + red[1]) + (red[2] + red[3]);
    __syncthreads();
    const float psum  = s_psum;
    const float denom = psum + EPSF;

    for (int e = tid; e < O_ * T9; e += 256) {
        const float4* q1 = (const float4*)(part1 + (size_t)(b * 288 + e) * PW);
        float s1 = 0.f;
#pragma unroll
        for (int i = 0; i < PW / 4; ++i) {
            const float4 v = q1[i];
            s1 += (v.x + v.y) + (v.z + v.w);
        }
        const float caps = s1 / denom;
        out[(size_t)b * 288 + e] = caps;
        w1[e] = caps * s1;
        w2[e] = caps * caps;
    }
    __syncthreads();

    if (tid < O_) {
        const int o = tid;
        const float4* q2 = (const float4*)(part2s + (size_t)(b * O_ + o) * PW);
        float s2 = 0.f;
#pragma unroll
        for (int i = 0; i < PW / 4; ++i) {
            const float4 v = q2[i];
            s2 += (v.x + v.y) + (v.z + v.w);
        }
        float d2 = 0.f, dc = 0.f;
#pragma unroll
        for (int t = 0; t < 9; ++t) { d2 += w1[o * 9 + t]; dc += w2[o * 9 + t]; }
        float vs = (s2 - 2.f * d2 + psum * dc) / denom;
        float mx = vs;
#pragma unroll
        for (int msk = 1; msk < 32; msk <<= 1) mx = fmaxf(mx, __shfl_xor(mx, msk, 32));
        out[(size_t)B_ * O_ * T9 + b * O_ + o] = 1.f - vs / (mx + EPSF);
    }
}

extern "C" void kernel_launch(void* const* d_in, const int* in_sizes, int n_in,
                              void* d_out, int out_size, void* d_ws, size_t ws_size,
                              hipStream_t stream)
{
    (void)in_sizes; (void)n_in; (void)out_size; (void)ws_size;
    const float* x = (const float*)d_in[0];   // (16,32,14,14,9)
    const float* p = (const float*)d_in[1];   // (16,32,14,14)
    // d_in[2] = epoch (unused)
    const float* T = (const float*)d_in[3];   // (1,32,32,14,14,9,9)
    float* out = (float*)d_out;

    float* part1  = (float*)d_ws;
    float* part2s = part1 + P1_N;
    float* xT     = part2s + P2_N;
    float* pT     = xT + XT_N;

    caps_pre<<<1024, 256, 0, stream>>>(x, p, xT, pT);
    dim3 gridA(O_, C_);   // o fast; same-c blocks adjacent -> L2 reuse of xT
    caps_main<<<gridA, 256, 0, stream>>>(T, xT, pT, part1, part2s);
    caps_final<<<B_, 256, 0, stream>>>(p, part1, part2s, out);
}